// Round 6
// baseline (297.911 us; speedup 1.0000x reference)
//
#include <hip/hip_runtime.h>

#define B_ 4
#define N_ 4096
#define DIM_ 512
#define H_ 8
#define DH_ 64
#define F_ 256
#define CS_ 128
#define M_ (B_*N_)         // 16384
#define NCHUNK_ 1024

typedef __attribute__((ext_vector_type(8))) short bf16x8;
typedef __attribute__((ext_vector_type(4))) float f32x4;

__device__ __forceinline__ unsigned short f2bf(float x){
  unsigned int u = __float_as_uint(x);
  u += 0x7fffu + ((u >> 16) & 1u);          // RNE
  return (unsigned short)(u >> 16);
}
__device__ __forceinline__ float bf2f(unsigned short s){
  return __uint_as_float(((unsigned int)s) << 16);
}
__device__ __forceinline__ unsigned pack2(float a, float b){
  return (unsigned)f2bf(a) | ((unsigned)f2bf(b) << 16);
}
__device__ __forceinline__ void gl2lds16(const unsigned short* g, unsigned short* l) {
  __builtin_amdgcn_global_load_lds((const __attribute__((address_space(1))) unsigned int*)g,
                                   (__attribute__((address_space(3))) unsigned int*)l,
                                   16, 0, 0);
}

// fp32 -> bf16 hi + lo
__global__ __launch_bounds__(256)
void split_kernel(const float* __restrict__ src, unsigned short* __restrict__ hi,
                  unsigned short* __restrict__ lo, int n4)
{
  int idx = blockIdx.x * 256 + threadIdx.x;
  if (idx >= n4) return;
  float4 v = ((const float4*)src)[idx];
  unsigned short h0 = f2bf(v.x), h1 = f2bf(v.y), h2 = f2bf(v.z), h3 = f2bf(v.w);
  unsigned short e0 = f2bf(v.x - bf2f(h0)), e1 = f2bf(v.y - bf2f(h1));
  unsigned short e2 = f2bf(v.z - bf2f(h2)), e3 = f2bf(v.w - bf2f(h3));
  uint2 hv, lv;
  hv.x = (unsigned)h0 | ((unsigned)h1 << 16); hv.y = (unsigned)h2 | ((unsigned)h3 << 16);
  lv.x = (unsigned)e0 | ((unsigned)e1 << 16); lv.y = (unsigned)e2 | ((unsigned)e3 << 16);
  ((uint2*)hi)[idx] = hv;
  ((uint2*)lo)[idx] = lv;
}

// proj fp32 [256][64] -> projk bf16, projq bf16 (pre-scaled by 0.125, exact pow2)
__global__ __launch_bounds__(256)
void prep_proj(const float* __restrict__ proj, unsigned short* __restrict__ pq,
               unsigned short* __restrict__ pk)
{
  int idx = blockIdx.x * 256 + threadIdx.x;   // float4 idx, 4096 total
  if (idx >= 4096) return;
  float4 v = ((const float4*)proj)[idx];
  uint2 k, q;
  k.x = pack2(v.x, v.y);           k.y = pack2(v.z, v.w);
  q.x = pack2(v.x*0.125f, v.y*0.125f); q.y = pack2(v.z*0.125f, v.w*0.125f);
  ((uint2*)pk)[idx] = k;
  ((uint2*)pq)[idx] = q;
}

// C[m][n] = sum_k A[m][k]*B[n][k]. SPLIT: 3-term bf16 emu of fp32.
// OUT: 0=f32(+bias), 1=bf16, 2=v-transpose hi/lo split into vth/vtl (swizzled chunk layout).
template<int SPLIT, int OUT>
__global__ __launch_bounds__(256, 2)
void mfma_gemm_nt(const unsigned short* __restrict__ Ahi, const unsigned short* __restrict__ Alo,
                  const unsigned short* __restrict__ Bhi, const unsigned short* __restrict__ Blo,
                  void* __restrict__ Cm, const float* __restrict__ bias, int K, int ldc,
                  unsigned short* __restrict__ vth, unsigned short* __restrict__ vtl)
{
  __shared__ __align__(16) unsigned short sAhi[4096];
  __shared__ __align__(16) unsigned short sBhi[4096];
  __shared__ __align__(16) unsigned short sAlo[4096];
  __shared__ __align__(16) unsigned short sBlo[4096];
  const int tid = threadIdx.x, lane = tid & 63, wave = tid >> 6;
  const int bm = blockIdx.y * 128, bn = blockIdx.x * 128;
  const int srow0 = wave * 32 + (lane >> 2);
  const int srow1 = srow0 + 16;
  const int slot = lane & 3;
  const int g0 = slot ^ ((srow0 >> 1) & 3);
  const int g1 = slot ^ ((srow1 >> 1) & 3);
  const size_t aOff0 = (size_t)(bm + srow0) * K + g0 * 8;
  const size_t aOff1 = (size_t)(bm + srow1) * K + g1 * 8;
  const size_t bOff0 = (size_t)(bn + srow0) * K + g0 * 8;
  const size_t bOff1 = (size_t)(bn + srow1) * K + g1 * 8;
  const int l0 = wave * 1024, l1 = wave * 1024 + 512;
  const int fr = lane & 15, quad = lane >> 4;
  const int wr = (wave >> 1) * 64, wc = (wave & 1) * 64;
  int offA[4], offB[4];
#pragma unroll
  for (int i = 0; i < 4; ++i) {
    int ra = wr + i * 16 + fr;  offA[i] = ra * 32 + (quad ^ ((ra >> 1) & 3)) * 8;
    int rb = wc + i * 16 + fr;  offB[i] = rb * 32 + (quad ^ ((rb >> 1) & 3)) * 8;
  }
  f32x4 acc[4][4];
#pragma unroll
  for (int i = 0; i < 4; ++i)
#pragma unroll
    for (int j = 0; j < 4; ++j) acc[i][j] = {0.f, 0.f, 0.f, 0.f};

  for (int k0 = 0; k0 < K; k0 += 32) {
    gl2lds16(Ahi + aOff0 + k0, &sAhi[l0]);
    gl2lds16(Ahi + aOff1 + k0, &sAhi[l1]);
    gl2lds16(Bhi + bOff0 + k0, &sBhi[l0]);
    gl2lds16(Bhi + bOff1 + k0, &sBhi[l1]);
    if (SPLIT) {
      gl2lds16(Alo + aOff0 + k0, &sAlo[l0]);
      gl2lds16(Alo + aOff1 + k0, &sAlo[l1]);
      gl2lds16(Blo + bOff0 + k0, &sBlo[l0]);
      gl2lds16(Blo + bOff1 + k0, &sBlo[l1]);
    }
    __syncthreads();
    bf16x8 ah[4], bh[4], al[4], bl[4];
#pragma unroll
    for (int i = 0; i < 4; ++i) {
      ah[i] = *(const bf16x8*)&sAhi[offA[i]];
      bh[i] = *(const bf16x8*)&sBhi[offB[i]];
      if (SPLIT) {
        al[i] = *(const bf16x8*)&sAlo[offA[i]];
        bl[i] = *(const bf16x8*)&sBlo[offB[i]];
      }
    }
#pragma unroll
    for (int i = 0; i < 4; ++i)
#pragma unroll
      for (int j = 0; j < 4; ++j) {
        acc[i][j] = __builtin_amdgcn_mfma_f32_16x16x32_bf16(ah[i], bh[j], acc[i][j], 0, 0, 0);
        if (SPLIT) {
          acc[i][j] = __builtin_amdgcn_mfma_f32_16x16x32_bf16(ah[i], bl[j], acc[i][j], 0, 0, 0);
          acc[i][j] = __builtin_amdgcn_mfma_f32_16x16x32_bf16(al[i], bh[j], acc[i][j], 0, 0, 0);
        }
      }
    __syncthreads();
  }
#pragma unroll
  for (int j = 0; j < 4; ++j) {
    int col = bn + wc + j * 16 + fr;
    float bv = (OUT == 0 && bias) ? bias[col] : 0.f;
#pragma unroll
    for (int i = 0; i < 4; ++i) {
      int row0 = bm + wr + i * 16 + quad * 4;
      if (OUT == 0) {
        float* cp = (float*)Cm + (size_t)row0 * ldc + col;
#pragma unroll
        for (int r = 0; r < 4; ++r) cp[(size_t)r * ldc] = acc[i][j][r] + bv;
      } else if (OUT == 1) {
        unsigned short* cp = (unsigned short*)Cm + (size_t)row0 * ldc + col;
#pragma unroll
        for (int r = 0; r < 4; ++r) cp[(size_t)r * ldc] = f2bf(acc[i][j][r]);
      } else {
        // v-transpose: col = d_global, rows = 4 consecutive tokens (= consecutive s)
        int hh = col >> 6, d = col & 63;
        int bb = row0 >> 12, cc2 = (row0 >> 7) & 31, s = row0 & 127;
        int ck = bb * 256 + hh * 32 + cc2;
        size_t ad = (size_t)ck * 8192 + d * 128 + (((s >> 3) ^ (d & 15)) << 3) + (s & 7);
        float v0 = acc[i][j][0], v1 = acc[i][j][1], v2 = acc[i][j][2], v3 = acc[i][j][3];
        unsigned short h0 = f2bf(v0), h1 = f2bf(v1), h2 = f2bf(v2), h3 = f2bf(v3);
        uint2 hv, lv;
        hv.x = (unsigned)h0 | ((unsigned)h1 << 16);
        hv.y = (unsigned)h2 | ((unsigned)h3 << 16);
        lv.x = pack2(v0 - bf2f(h0), v1 - bf2f(h1));
        lv.y = pack2(v2 - bf2f(h2), v3 - bf2f(h3));
        *(uint2*)(vth + ad) = hv;
        *(uint2*)(vtl + ad) = lv;
      }
    }
  }
}

// Fully fused per-chunk Performer kernel, 512 threads (8 waves) for latency hiding.
// k-pass -> q-pass -> ctx (2 vt passes) -> D -> out. Intermediates stay in LDS.
__global__ __launch_bounds__(512, 1)
void fused_chunk(const unsigned short* __restrict__ qkv_bf,
                 const unsigned short* __restrict__ projq,
                 const unsigned short* __restrict__ projk,
                 const unsigned short* __restrict__ vth_g,
                 const unsigned short* __restrict__ vtl_g,
                 unsigned short* __restrict__ attn_hi,
                 unsigned short* __restrict__ attn_lo)
{
  __shared__ __align__(16) char smem[157184];
  unsigned short* KPT = (unsigned short*)smem;            // [256 f][128 s] swz -> later ctx hi/lo
  unsigned short* QP  = (unsigned short*)(smem + 65536);  // [128 s][256 f] swz
  unsigned short* X   = (unsigned short*)(smem + 131072); // 16 KB bounce: t_k / t_q / vth / vtl
  float* KS  = (float*)(smem + 147456);                   // [256]
  float* DI  = (float*)(smem + 148480);                   // [128]
  float* KSP = (float*)(smem + 148992);                   // [8][256]; reused as DP[2][128] in phase 8

  const int tid = threadIdx.x, lane = tid & 63, wave = tid >> 6;   // 8 waves
  const int fr = lane & 15, quad = lane >> 4;
  const int chunk = blockIdx.x;
  const int b = chunk >> 8, h = (chunk >> 5) & 7, cc = chunk & 31;
  const int mbase = b * N_ + cc * CS_;

  // ---- phase 1: stage t_k into X ----
#pragma unroll
  for (int j = 0; j < 4; ++j) {
    int idx = tid + j * 512;                 // uint2 units, 2048 total
    int s = idx >> 4, d0 = (idx & 15) * 4;
    uint2 v = *(const uint2*)(qkv_bf + (size_t)(mbase + s) * 1024 + 512 + h * DH_ + d0);
    *(uint2*)(X + s * 64 + (((d0 >> 3) ^ (s & 7)) << 3) + (d0 & 7)) = v;
  }
  __syncthreads();

  // ---- phase 2: k-pass: C[s][f] = t_k @ projk^T, rowmax, exp, write kpT + KSP ----
  {
    f32x4 ka[16];
#pragma unroll
    for (int nt = 0; nt < 16; ++nt) ka[nt] = {0.f, 0.f, 0.f, 0.f};
#pragma unroll
    for (int ks = 0; ks < 2; ++ks) {
      int s = wave * 16 + fr;
      bf16x8 a = *(const bf16x8*)(X + s * 64 + (((ks * 4 + quad) ^ (s & 7)) << 3));
#pragma unroll
      for (int nt = 0; nt < 16; ++nt) {
        bf16x8 bf = *(const bf16x8*)(projk + (size_t)(nt * 16 + fr) * 64 + ks * 32 + quad * 8);
        ka[nt] = __builtin_amdgcn_mfma_f32_16x16x32_bf16(a, bf, ka[nt], 0, 0, 0);
      }
    }
#pragma unroll
    for (int r = 0; r < 4; ++r) {
      float m = ka[0][r];
#pragma unroll
      for (int nt = 1; nt < 16; ++nt) m = fmaxf(m, ka[nt][r]);
      m = fmaxf(m, __shfl_xor(m, 1, 16));
      m = fmaxf(m, __shfl_xor(m, 2, 16));
      m = fmaxf(m, __shfl_xor(m, 4, 16));
      m = fmaxf(m, __shfl_xor(m, 8, 16));
#pragma unroll
      for (int nt = 0; nt < 16; ++nt) ka[nt][r] = __expf(ka[nt][r] - m);
    }
    // ksum partials (sum over this wave's 16 s)
#pragma unroll
    for (int nt = 0; nt < 16; ++nt) {
      float sm = ka[nt][0] + ka[nt][1] + ka[nt][2] + ka[nt][3];
      sm += __shfl_xor(sm, 16, 64);
      sm += __shfl_xor(sm, 32, 64);
      if (quad == 0) KSP[wave * 256 + nt * 16 + fr] = sm;
    }
    // kpT[f][s] write (4 consecutive s per lane)
    const int g = wave * 2 + (quad >> 1);          // s>>3
#pragma unroll
    for (int nt = 0; nt < 16; ++nt) {
      int f = nt * 16 + fr;
      uint2 w;
      w.x = pack2(ka[nt][0], ka[nt][1]);
      w.y = pack2(ka[nt][2], ka[nt][3]);
      *(uint2*)(KPT + f * 128 + ((g ^ (f & 15)) << 3) + (quad & 1) * 4) = w;
    }
  }
  __syncthreads();

  // ---- phase 3: KS reduce + stage t_q into X ----
  if (tid < 256) {
    float s0 = KSP[tid]       + KSP[256 + tid]  + KSP[512 + tid]  + KSP[768 + tid];
    float s1 = KSP[1024 + tid] + KSP[1280 + tid] + KSP[1536 + tid] + KSP[1792 + tid];
    KS[tid] = s0 + s1;
  }
#pragma unroll
  for (int j = 0; j < 4; ++j) {
    int idx = tid + j * 512;
    int s = idx >> 4, d0 = (idx & 15) * 4;
    uint2 v = *(const uint2*)(qkv_bf + (size_t)(mbase + s) * 1024 + h * DH_ + d0);
    *(uint2*)(X + s * 64 + (((d0 >> 3) ^ (s & 7)) << 3) + (d0 & 7)) = v;
  }
  __syncthreads();

  // ---- phase 4: q-pass: C[f][s] = projq @ t_q^T, colmax(f), exp, write qp ----
  {
    f32x4 qa[16];
#pragma unroll
    for (int mt = 0; mt < 16; ++mt) qa[mt] = {0.f, 0.f, 0.f, 0.f};
#pragma unroll
    for (int ks = 0; ks < 2; ++ks) {
      int s = wave * 16 + fr;
      bf16x8 bfr = *(const bf16x8*)(X + s * 64 + (((ks * 4 + quad) ^ (s & 7)) << 3));
#pragma unroll
      for (int mt = 0; mt < 16; ++mt) {
        bf16x8 af = *(const bf16x8*)(projq + (size_t)(mt * 16 + fr) * 64 + ks * 32 + quad * 8);
        qa[mt] = __builtin_amdgcn_mfma_f32_16x16x32_bf16(af, bfr, qa[mt], 0, 0, 0);
      }
    }
    {
      float m = -1e30f;
#pragma unroll
      for (int mt = 0; mt < 16; ++mt)
#pragma unroll
        for (int r = 0; r < 4; ++r) m = fmaxf(m, qa[mt][r]);
      m = fmaxf(m, __shfl_xor(m, 16, 64));
      m = fmaxf(m, __shfl_xor(m, 32, 64));
#pragma unroll
      for (int mt = 0; mt < 16; ++mt)
#pragma unroll
        for (int r = 0; r < 4; ++r) qa[mt][r] = __expf(qa[mt][r] - m);
    }
    // qp[s][f] write (4 consecutive f per lane)
    const int s = wave * 16 + fr;
#pragma unroll
    for (int mt = 0; mt < 16; ++mt) {
      int g = mt * 2 + (quad >> 1);               // f>>3
      uint2 w;
      w.x = pack2(qa[mt][0], qa[mt][1]);
      w.y = pack2(qa[mt][2], qa[mt][3]);
      *(uint2*)(QP + s * 256 + ((g ^ (s & 15)) << 3) + (quad & 1) * 4) = w;
    }
  }
  __syncthreads();

  // ---- phase 5: step A, pass 1 (v hi): ctx[f][d] += kpT @ vth^T ----
  const unsigned short* vhs = vth_g + (size_t)chunk * 8192;
  const unsigned short* vls = vtl_g + (size_t)chunk * 8192;
#pragma unroll
  for (int i = 0; i < 2; ++i) gl2lds16(vhs + (wave*2+i)*512 + lane*8, X + (wave*2+i)*512);
  __syncthreads();

  f32x4 acc_a[2][4];
#pragma unroll
  for (int i = 0; i < 2; ++i)
#pragma unroll
    for (int j = 0; j < 4; ++j) acc_a[i][j] = {0.f, 0.f, 0.f, 0.f};
#pragma unroll
  for (int ks = 0; ks < 4; ++ks) {
    int l = ks * 4 + quad;
    bf16x8 a[2];
#pragma unroll
    for (int mt = 0; mt < 2; ++mt) {
      int f = wave * 32 + mt * 16 + fr;
      a[mt] = *(const bf16x8*)(KPT + f * 128 + ((l ^ (f & 15)) << 3));
    }
#pragma unroll
    for (int nt = 0; nt < 4; ++nt) {
      int d = nt * 16 + fr;
      bf16x8 bh = *(const bf16x8*)(X + d * 128 + ((l ^ (d & 15)) << 3));
#pragma unroll
      for (int mt = 0; mt < 2; ++mt)
        acc_a[mt][nt] = __builtin_amdgcn_mfma_f32_16x16x32_bf16(a[mt], bh, acc_a[mt][nt], 0, 0, 0);
    }
  }
  __syncthreads();
  // ---- phase 6: step A, pass 2 (v lo) ----
#pragma unroll
  for (int i = 0; i < 2; ++i) gl2lds16(vls + (wave*2+i)*512 + lane*8, X + (wave*2+i)*512);
  __syncthreads();
#pragma unroll
  for (int ks = 0; ks < 4; ++ks) {
    int l = ks * 4 + quad;
    bf16x8 a[2];
#pragma unroll
    for (int mt = 0; mt < 2; ++mt) {
      int f = wave * 32 + mt * 16 + fr;
      a[mt] = *(const bf16x8*)(KPT + f * 128 + ((l ^ (f & 15)) << 3));
    }
#pragma unroll
    for (int nt = 0; nt < 4; ++nt) {
      int d = nt * 16 + fr;
      bf16x8 bl = *(const bf16x8*)(X + d * 128 + ((l ^ (d & 15)) << 3));
#pragma unroll
      for (int mt = 0; mt < 2; ++mt)
        acc_a[mt][nt] = __builtin_amdgcn_mfma_f32_16x16x32_bf16(a[mt], bl, acc_a[mt][nt], 0, 0, 0);
    }
  }
  __syncthreads();   // all kpT reads done before ctx overwrites it

  // ---- phase 7: ctx hi/lo -> LDS over KPT region ([64 d][256 f], hi@0, lo@16384) ----
#pragma unroll
  for (int mt = 0; mt < 2; ++mt)
#pragma unroll
    for (int nt = 0; nt < 4; ++nt) {
      int d = nt * 16 + fr;
      int g = wave * 4 + mt * 2 + (quad >> 1);      // f>>3
      float v0 = acc_a[mt][nt][0], v1 = acc_a[mt][nt][1];
      float v2 = acc_a[mt][nt][2], v3 = acc_a[mt][nt][3];
      unsigned short h0 = f2bf(v0), h1 = f2bf(v1), h2 = f2bf(v2), h3 = f2bf(v3);
      uint2 whi, wlo;
      whi.x = (unsigned)h0 | ((unsigned)h1 << 16);
      whi.y = (unsigned)h2 | ((unsigned)h3 << 16);
      wlo.x = pack2(v0 - bf2f(h0), v1 - bf2f(h1));
      wlo.y = pack2(v2 - bf2f(h2), v3 - bf2f(h3));
      int ad = d * 256 + ((g ^ (d & 15)) << 3) + (quad & 1) * 4;
      *(uint2*)(KPT + ad) = whi;
      *(uint2*)(KPT + 16384 + ad) = wlo;
    }
  __syncthreads();

  // ---- phase 8: D = qp . ksum (two f-halves in parallel) ----
  float* DP = KSP;   // reuse (dead after phase 3)
  if (tid < 256) {
    int s = tid & 127, hf = tid >> 7;
    float dp = 0.f;
#pragma unroll 4
    for (int li = 0; li < 16; ++li) {
      int l = hf * 16 + li;
      bf16x8 qv = *(const bf16x8*)(QP + s * 256 + ((l ^ (s & 15)) << 3));
      f32x4 k0 = *(const f32x4*)(KS + l * 8);
      f32x4 k1 = *(const f32x4*)(KS + l * 8 + 4);
      dp += bf2f((unsigned short)qv[0]) * k0[0];
      dp += bf2f((unsigned short)qv[1]) * k0[1];
      dp += bf2f((unsigned short)qv[2]) * k0[2];
      dp += bf2f((unsigned short)qv[3]) * k0[3];
      dp += bf2f((unsigned short)qv[4]) * k1[0];
      dp += bf2f((unsigned short)qv[5]) * k1[1];
      dp += bf2f((unsigned short)qv[6]) * k1[2];
      dp += bf2f((unsigned short)qv[7]) * k1[3];
    }
    DP[hf * 128 + s] = dp;
  }
  __syncthreads();
  if (tid < 128) DI[tid] = 1.f / (DP[tid] + DP[128 + tid] + 1e-4f);
  __syncthreads();

  // ---- phase 9: step B: C[m=d][n=s] = sum_f ctx[d][f]*qp[s][f]; scale; store ----
  f32x4 acc2[4];
#pragma unroll
  for (int i = 0; i < 4; ++i) acc2[i] = {0.f, 0.f, 0.f, 0.f};
#pragma unroll
  for (int ks = 0; ks < 8; ++ks) {
    int l = ks * 4 + quad;
    int s = wave * 16 + fr;
    bf16x8 bq = *(const bf16x8*)(QP + s * 256 + ((l ^ (s & 15)) << 3));
#pragma unroll
    for (int mt = 0; mt < 4; ++mt) {
      int d = mt * 16 + fr;
      int ad = d * 256 + ((l ^ (d & 15)) << 3);
      bf16x8 ah = *(const bf16x8*)(KPT + ad);
      bf16x8 al = *(const bf16x8*)(KPT + 16384 + ad);
      acc2[mt] = __builtin_amdgcn_mfma_f32_16x16x32_bf16(ah, bq, acc2[mt], 0, 0, 0);
      acc2[mt] = __builtin_amdgcn_mfma_f32_16x16x32_bf16(al, bq, acc2[mt], 0, 0, 0);
    }
  }
  {
    int s = wave * 16 + fr;
    float di = DI[s];
    size_t base = (size_t)(mbase + s) * 512 + h * DH_;
#pragma unroll
    for (int mt = 0; mt < 4; ++mt) {
      int d0 = mt * 16 + quad * 4;
      float o0 = acc2[mt][0] * di, o1 = acc2[mt][1] * di;
      float o2 = acc2[mt][2] * di, o3 = acc2[mt][3] * di;
      unsigned short h0 = f2bf(o0), h1 = f2bf(o1), h2 = f2bf(o2), h3 = f2bf(o3);
      uint2 whi, wlo;
      whi.x = (unsigned)h0 | ((unsigned)h1 << 16);
      whi.y = (unsigned)h2 | ((unsigned)h3 << 16);
      wlo.x = pack2(o0 - bf2f(h0), o1 - bf2f(h1));
      wlo.y = pack2(o2 - bf2f(h2), o3 - bf2f(h3));
      *(uint2*)(attn_hi + base + d0) = whi;
      *(uint2*)(attn_lo + base + d0) = wlo;
    }
  }
}

extern "C" void kernel_launch(void* const* d_in, const int* in_sizes, int n_in,
                              void* d_out, int out_size, void* d_ws, size_t ws_size,
                              hipStream_t stream)
{
  const float* x     = (const float*)d_in[0];
  const float* w_qkv = (const float*)d_in[1];
  const float* w_out = (const float*)d_in[2];
  const float* b_out = (const float*)d_in[3];
  const float* proj  = (const float*)d_in[4];
  float* out = (float*)d_out;

  // ws layout (235,929,600 B total):
  //  R0 @0:          qkv_bf bf16 [16384][1024] (q,k)   33,554,432
  //  R1 @33554432:   x_hi/x_lo bf16 [16384][512] each  33,554,432  -> later projq/projk + wout splits
  //  R2 @67108864:   wqkv splits (3 MB)                            (rest free)
  //  R3 @134217728:  attn_hi, attn_lo bf16 [16384][512] 33,554,432
  //  R4 @201326592:  vt_hi, vt_lo bf16 [1024][64][128] 33,554,432  (written by gemm_v epilogue)
  char* ws = (char*)d_ws;
  unsigned short* qkv_bf = (unsigned short*)ws;
  unsigned short* x_hi   = (unsigned short*)(ws + 33554432);
  unsigned short* x_lo   = x_hi + (size_t)M_ * DIM_;
  unsigned short* wqkv_hi = (unsigned short*)(ws + 67108864);
  unsigned short* wqkv_lo = wqkv_hi + (size_t)(3*DIM_) * DIM_;
  unsigned short* attn_hi = (unsigned short*)(ws + 134217728);
  unsigned short* attn_lo = attn_hi + (size_t)M_ * DIM_;
  unsigned short* vth_g  = (unsigned short*)(ws + 201326592);
  unsigned short* vtl_g  = (unsigned short*)(ws + 218103808);

  unsigned short* projq = x_hi;                         // x splits dead after gemm_v
  unsigned short* projk = projq + 16384;
  unsigned short* wout_hi = projk + 16384;
  unsigned short* wout_lo = wout_hi + (size_t)DIM_ * DIM_;

  // 1) splits
  split_kernel<<<dim3(M_*DIM_/4/256), 256, 0, stream>>>(x, x_hi, x_lo, M_*DIM_/4);
  split_kernel<<<dim3(3*DIM_*DIM_/4/256), 256, 0, stream>>>(w_qkv, wqkv_hi, wqkv_lo, 3*DIM_*DIM_/4);
  // 2) q,k = x @ w_qkv[0:1024]^T  (single bf16, bf16 out)
  mfma_gemm_nt<0,1><<<dim3(8, M_/128), 256, 0, stream>>>(
      x_hi, x_hi, wqkv_hi, wqkv_hi, qkv_bf, nullptr, DIM_, 1024, nullptr, nullptr);
  // 3) v = x @ w_qkv[1024:1536]^T (split) -> transposed hi/lo chunk layout directly
  mfma_gemm_nt<1,2><<<dim3(4, M_/128), 256, 0, stream>>>(
      x_hi, x_lo, wqkv_hi + (size_t)1024*DIM_, wqkv_lo + (size_t)1024*DIM_,
      nullptr, nullptr, DIM_, 0, vth_g, vtl_g);
  // 4) proj -> bf16 (q pre-scaled by 1/8); x splits dead now
  prep_proj<<<dim3(16), 256, 0, stream>>>(proj, projq, projk);
  // 5) fully fused per-chunk Performer (512 threads, 8 waves)
  fused_chunk<<<dim3(NCHUNK_), 512, 0, stream>>>(qkv_bf, projq, projk, vth_g, vtl_g,
                                                 attn_hi, attn_lo);
  // 6) w_out split, then out = attn @ w_out^T + b_out (split)
  split_kernel<<<dim3(DIM_*DIM_/4/256), 256, 0, stream>>>(w_out, wout_hi, wout_lo, DIM_*DIM_/4);
  mfma_gemm_nt<1,0><<<dim3(4, M_/128), 256, 0, stream>>>(
      attn_hi, attn_lo, wout_hi, wout_lo, out, b_out, DIM_, DIM_, nullptr, nullptr);
}

// Round 7
// 297.567 us; speedup vs baseline: 1.0012x; 1.0012x over previous
//
#include <hip/hip_runtime.h>

#define B_ 4
#define N_ 4096
#define DIM_ 512
#define H_ 8
#define DH_ 64
#define F_ 256
#define CS_ 128
#define M_ (B_*N_)         // 16384
#define NCHUNK_ 1024

typedef __attribute__((ext_vector_type(8))) short bf16x8;
typedef __attribute__((ext_vector_type(4))) float f32x4;

__device__ __forceinline__ unsigned short f2bf(float x){
  unsigned int u = __float_as_uint(x);
  u += 0x7fffu + ((u >> 16) & 1u);          // RNE
  return (unsigned short)(u >> 16);
}
__device__ __forceinline__ float bf2f(unsigned short s){
  return __uint_as_float(((unsigned int)s) << 16);
}
__device__ __forceinline__ unsigned pack2(float a, float b){
  return (unsigned)f2bf(a) | ((unsigned)f2bf(b) << 16);
}
__device__ __forceinline__ void gl2lds16(const unsigned short* g, unsigned short* l) {
  __builtin_amdgcn_global_load_lds((const __attribute__((address_space(1))) unsigned int*)g,
                                   (__attribute__((address_space(3))) unsigned int*)l,
                                   16, 0, 0);
}

// fp32 -> bf16 hi + lo
__global__ __launch_bounds__(256)
void split_kernel(const float* __restrict__ src, unsigned short* __restrict__ hi,
                  unsigned short* __restrict__ lo, int n4)
{
  int idx = blockIdx.x * 256 + threadIdx.x;
  if (idx >= n4) return;
  float4 v = ((const float4*)src)[idx];
  unsigned short h0 = f2bf(v.x), h1 = f2bf(v.y), h2 = f2bf(v.z), h3 = f2bf(v.w);
  unsigned short e0 = f2bf(v.x - bf2f(h0)), e1 = f2bf(v.y - bf2f(h1));
  unsigned short e2 = f2bf(v.z - bf2f(h2)), e3 = f2bf(v.w - bf2f(h3));
  uint2 hv, lv;
  hv.x = (unsigned)h0 | ((unsigned)h1 << 16); hv.y = (unsigned)h2 | ((unsigned)h3 << 16);
  lv.x = (unsigned)e0 | ((unsigned)e1 << 16); lv.y = (unsigned)e2 | ((unsigned)e3 << 16);
  ((uint2*)hi)[idx] = hv;
  ((uint2*)lo)[idx] = lv;
}

// proj fp32 [256][64] -> projk bf16, projq bf16 (pre-scaled by 0.125, exact pow2)
__global__ __launch_bounds__(256)
void prep_proj(const float* __restrict__ proj, unsigned short* __restrict__ pq,
               unsigned short* __restrict__ pk)
{
  int idx = blockIdx.x * 256 + threadIdx.x;   // float4 idx, 4096 total
  if (idx >= 4096) return;
  float4 v = ((const float4*)proj)[idx];
  uint2 k, q;
  k.x = pack2(v.x, v.y);           k.y = pack2(v.z, v.w);
  q.x = pack2(v.x*0.125f, v.y*0.125f); q.y = pack2(v.z*0.125f, v.w*0.125f);
  ((uint2*)pk)[idx] = k;
  ((uint2*)pq)[idx] = q;
}

// C[m][n] = sum_k A[m][k]*B[n][k]. SPLIT: 3-term bf16 emu of fp32.
// OUT: 0=f32(+bias), 1=bf16, 2=v-transpose hi/lo split into vth/vtl (swizzled chunk layout).
template<int SPLIT, int OUT>
__global__ __launch_bounds__(256, 2)
void mfma_gemm_nt(const unsigned short* __restrict__ Ahi, const unsigned short* __restrict__ Alo,
                  const unsigned short* __restrict__ Bhi, const unsigned short* __restrict__ Blo,
                  void* __restrict__ Cm, const float* __restrict__ bias, int K, int ldc,
                  unsigned short* __restrict__ vth, unsigned short* __restrict__ vtl)
{
  __shared__ __align__(16) unsigned short sAhi[4096];
  __shared__ __align__(16) unsigned short sBhi[4096];
  __shared__ __align__(16) unsigned short sAlo[4096];
  __shared__ __align__(16) unsigned short sBlo[4096];
  const int tid = threadIdx.x, lane = tid & 63, wave = tid >> 6;
  const int bm = blockIdx.y * 128, bn = blockIdx.x * 128;
  const int srow0 = wave * 32 + (lane >> 2);
  const int srow1 = srow0 + 16;
  const int slot = lane & 3;
  const int g0 = slot ^ ((srow0 >> 1) & 3);
  const int g1 = slot ^ ((srow1 >> 1) & 3);
  const size_t aOff0 = (size_t)(bm + srow0) * K + g0 * 8;
  const size_t aOff1 = (size_t)(bm + srow1) * K + g1 * 8;
  const size_t bOff0 = (size_t)(bn + srow0) * K + g0 * 8;
  const size_t bOff1 = (size_t)(bn + srow1) * K + g1 * 8;
  const int l0 = wave * 1024, l1 = wave * 1024 + 512;
  const int fr = lane & 15, quad = lane >> 4;
  const int wr = (wave >> 1) * 64, wc = (wave & 1) * 64;
  int offA[4], offB[4];
#pragma unroll
  for (int i = 0; i < 4; ++i) {
    int ra = wr + i * 16 + fr;  offA[i] = ra * 32 + (quad ^ ((ra >> 1) & 3)) * 8;
    int rb = wc + i * 16 + fr;  offB[i] = rb * 32 + (quad ^ ((rb >> 1) & 3)) * 8;
  }
  f32x4 acc[4][4];
#pragma unroll
  for (int i = 0; i < 4; ++i)
#pragma unroll
    for (int j = 0; j < 4; ++j) acc[i][j] = {0.f, 0.f, 0.f, 0.f};

  for (int k0 = 0; k0 < K; k0 += 32) {
    gl2lds16(Ahi + aOff0 + k0, &sAhi[l0]);
    gl2lds16(Ahi + aOff1 + k0, &sAhi[l1]);
    gl2lds16(Bhi + bOff0 + k0, &sBhi[l0]);
    gl2lds16(Bhi + bOff1 + k0, &sBhi[l1]);
    if (SPLIT) {
      gl2lds16(Alo + aOff0 + k0, &sAlo[l0]);
      gl2lds16(Alo + aOff1 + k0, &sAlo[l1]);
      gl2lds16(Blo + bOff0 + k0, &sBlo[l0]);
      gl2lds16(Blo + bOff1 + k0, &sBlo[l1]);
    }
    __syncthreads();
    bf16x8 ah[4], bh[4], al[4], bl[4];
#pragma unroll
    for (int i = 0; i < 4; ++i) {
      ah[i] = *(const bf16x8*)&sAhi[offA[i]];
      bh[i] = *(const bf16x8*)&sBhi[offB[i]];
      if (SPLIT) {
        al[i] = *(const bf16x8*)&sAlo[offA[i]];
        bl[i] = *(const bf16x8*)&sBlo[offB[i]];
      }
    }
#pragma unroll
    for (int i = 0; i < 4; ++i)
#pragma unroll
      for (int j = 0; j < 4; ++j) {
        acc[i][j] = __builtin_amdgcn_mfma_f32_16x16x32_bf16(ah[i], bh[j], acc[i][j], 0, 0, 0);
        if (SPLIT) {
          acc[i][j] = __builtin_amdgcn_mfma_f32_16x16x32_bf16(ah[i], bl[j], acc[i][j], 0, 0, 0);
          acc[i][j] = __builtin_amdgcn_mfma_f32_16x16x32_bf16(al[i], bh[j], acc[i][j], 0, 0, 0);
        }
      }
    __syncthreads();
  }
#pragma unroll
  for (int j = 0; j < 4; ++j) {
    int col = bn + wc + j * 16 + fr;
    float bv = (OUT == 0 && bias) ? bias[col] : 0.f;
#pragma unroll
    for (int i = 0; i < 4; ++i) {
      int row0 = bm + wr + i * 16 + quad * 4;
      if (OUT == 0) {
        float* cp = (float*)Cm + (size_t)row0 * ldc + col;
#pragma unroll
        for (int r = 0; r < 4; ++r) cp[(size_t)r * ldc] = acc[i][j][r] + bv;
      } else if (OUT == 1) {
        unsigned short* cp = (unsigned short*)Cm + (size_t)row0 * ldc + col;
#pragma unroll
        for (int r = 0; r < 4; ++r) cp[(size_t)r * ldc] = f2bf(acc[i][j][r]);
      } else {
        // v-transpose: col = d_global, rows = 4 consecutive tokens (= consecutive s)
        int hh = col >> 6, d = col & 63;
        int bb = row0 >> 12, cc2 = (row0 >> 7) & 31, s = row0 & 127;
        int ck = bb * 256 + hh * 32 + cc2;
        size_t ad = (size_t)ck * 8192 + d * 128 + (((s >> 3) ^ (d & 15)) << 3) + (s & 7);
        float v0 = acc[i][j][0], v1 = acc[i][j][1], v2 = acc[i][j][2], v3 = acc[i][j][3];
        unsigned short h0 = f2bf(v0), h1 = f2bf(v1), h2 = f2bf(v2), h3 = f2bf(v3);
        uint2 hv, lv;
        hv.x = (unsigned)h0 | ((unsigned)h1 << 16);
        hv.y = (unsigned)h2 | ((unsigned)h3 << 16);
        lv.x = pack2(v0 - bf2f(h0), v1 - bf2f(h1));
        lv.y = pack2(v2 - bf2f(h2), v3 - bf2f(h3));
        *(uint2*)(vth + ad) = hv;
        *(uint2*)(vtl + ad) = lv;
      }
    }
  }
}

// chunkA: k-pass (A-frags direct from global) -> kpT(LDS) + ksum(global);
// step A (vth/vtl via X bounce) -> ctx hi/lo to global, linear [64 d][256 f] per chunk.
// LDS = 64K (KPT) + 16K (X, KSP overlaid) = 80KB -> 2 blocks/CU.
__global__ __launch_bounds__(256, 2)
void chunkA(const unsigned short* __restrict__ qkv_bf,
            const unsigned short* __restrict__ projk,
            const unsigned short* __restrict__ vth_g,
            const unsigned short* __restrict__ vtl_g,
            unsigned short* __restrict__ ctxh_g,
            unsigned short* __restrict__ ctxl_g,
            float* __restrict__ ksum_g)
{
  __shared__ __align__(16) char smem[81920];
  unsigned short* KPT = (unsigned short*)smem;            // [256 f][128 s] swz
  unsigned short* X   = (unsigned short*)(smem + 65536);  // 16 KB bounce (vth/vtl)
  float* KSP = (float*)(smem + 65536);                    // [4][256] overlaid in X (pre-vt)

  const int tid = threadIdx.x, lane = tid & 63, wave = tid >> 6;
  const int fr = lane & 15, quad = lane >> 4;
  const int chunk = blockIdx.x;
  const int b = chunk >> 8, h = (chunk >> 5) & 7, cc = chunk & 31;
  const int mbase = b * N_ + cc * CS_;
  const unsigned short* tkbase = qkv_bf + (size_t)mbase * 1024 + 512 + h * DH_;

  // ---- k-pass: C[s][f] = t_k @ projk^T (A-frags direct from global) ----
  {
    bf16x8 a[2][2];
#pragma unroll
    for (int mt = 0; mt < 2; ++mt)
#pragma unroll
      for (int ks = 0; ks < 2; ++ks) {
        int s = wave * 32 + mt * 16 + fr;
        a[mt][ks] = *(const bf16x8*)(tkbase + (size_t)s * 1024 + ks * 32 + quad * 8);
      }
    f32x4 ka[2][16];
#pragma unroll
    for (int nt = 0; nt < 16; ++nt) { ka[0][nt] = {0,0,0,0}; ka[1][nt] = {0,0,0,0}; }
#pragma unroll
    for (int ks = 0; ks < 2; ++ks)
#pragma unroll
      for (int nt = 0; nt < 16; ++nt) {
        bf16x8 bf = *(const bf16x8*)(projk + (size_t)(nt * 16 + fr) * 64 + ks * 32 + quad * 8);
        ka[0][nt] = __builtin_amdgcn_mfma_f32_16x16x32_bf16(a[0][ks], bf, ka[0][nt], 0, 0, 0);
        ka[1][nt] = __builtin_amdgcn_mfma_f32_16x16x32_bf16(a[1][ks], bf, ka[1][nt], 0, 0, 0);
      }
    // rowmax over f, exp
#pragma unroll
    for (int mt = 0; mt < 2; ++mt)
#pragma unroll
      for (int r = 0; r < 4; ++r) {
        float m = ka[mt][0][r];
#pragma unroll
        for (int nt = 1; nt < 16; ++nt) m = fmaxf(m, ka[mt][nt][r]);
        m = fmaxf(m, __shfl_xor(m, 1, 16));
        m = fmaxf(m, __shfl_xor(m, 2, 16));
        m = fmaxf(m, __shfl_xor(m, 4, 16));
        m = fmaxf(m, __shfl_xor(m, 8, 16));
#pragma unroll
        for (int nt = 0; nt < 16; ++nt) ka[mt][nt][r] = __expf(ka[mt][nt][r] - m);
      }
    // ksum partials
#pragma unroll
    for (int nt = 0; nt < 16; ++nt) {
      float sm = 0.f;
#pragma unroll
      for (int mt = 0; mt < 2; ++mt)
#pragma unroll
        for (int r = 0; r < 4; ++r) sm += ka[mt][nt][r];
      sm += __shfl_xor(sm, 16, 64);
      sm += __shfl_xor(sm, 32, 64);
      if (quad == 0) KSP[wave * 256 + nt * 16 + fr] = sm;
    }
    // kpT[f][s] (4 consecutive s per lane)
#pragma unroll
    for (int nt = 0; nt < 16; ++nt) {
      int f = nt * 16 + fr;
#pragma unroll
      for (int mt = 0; mt < 2; ++mt) {
        int g = wave * 4 + mt * 2 + (quad >> 1);     // s>>3
        uint2 w;
        w.x = pack2(ka[mt][nt][0], ka[mt][nt][1]);
        w.y = pack2(ka[mt][nt][2], ka[mt][nt][3]);
        *(uint2*)(KPT + f * 128 + ((g ^ (f & 15)) << 3) + (quad & 1) * 4) = w;
      }
    }
  }
  __syncthreads();
  // ksum -> global (coalesced)
  ksum_g[(size_t)chunk * 256 + tid] =
      KSP[tid] + KSP[256 + tid] + KSP[512 + tid] + KSP[768 + tid];
  __syncthreads();   // KSP region free before vt staging

  // ---- step A pass 1 (v hi) ----
  const unsigned short* vhs = vth_g + (size_t)chunk * 8192;
  const unsigned short* vls = vtl_g + (size_t)chunk * 8192;
#pragma unroll
  for (int i = 0; i < 4; ++i) gl2lds16(vhs + (wave*4+i)*512 + lane*8, X + (wave*4+i)*512);
  __syncthreads();

  f32x4 acc_a[4][4];
#pragma unroll
  for (int i = 0; i < 4; ++i)
#pragma unroll
    for (int j = 0; j < 4; ++j) acc_a[i][j] = {0.f, 0.f, 0.f, 0.f};
#pragma unroll
  for (int ks = 0; ks < 4; ++ks) {
    int l = ks * 4 + quad;
    bf16x8 a[4];
#pragma unroll
    for (int mt = 0; mt < 4; ++mt) {
      int f = wave * 64 + mt * 16 + fr;
      a[mt] = *(const bf16x8*)(KPT + f * 128 + ((l ^ (f & 15)) << 3));
    }
#pragma unroll
    for (int nt = 0; nt < 4; ++nt) {
      int d = nt * 16 + fr;
      bf16x8 bh = *(const bf16x8*)(X + d * 128 + ((l ^ (d & 15)) << 3));
#pragma unroll
      for (int mt = 0; mt < 4; ++mt)
        acc_a[mt][nt] = __builtin_amdgcn_mfma_f32_16x16x32_bf16(a[mt], bh, acc_a[mt][nt], 0, 0, 0);
    }
  }
  __syncthreads();
  // ---- step A pass 2 (v lo) ----
#pragma unroll
  for (int i = 0; i < 4; ++i) gl2lds16(vls + (wave*4+i)*512 + lane*8, X + (wave*4+i)*512);
  __syncthreads();
#pragma unroll
  for (int ks = 0; ks < 4; ++ks) {
    int l = ks * 4 + quad;
    bf16x8 a[4];
#pragma unroll
    for (int mt = 0; mt < 4; ++mt) {
      int f = wave * 64 + mt * 16 + fr;
      a[mt] = *(const bf16x8*)(KPT + f * 128 + ((l ^ (f & 15)) << 3));
    }
#pragma unroll
    for (int nt = 0; nt < 4; ++nt) {
      int d = nt * 16 + fr;
      bf16x8 bl = *(const bf16x8*)(X + d * 128 + ((l ^ (d & 15)) << 3));
#pragma unroll
      for (int mt = 0; mt < 4; ++mt)
        acc_a[mt][nt] = __builtin_amdgcn_mfma_f32_16x16x32_bf16(a[mt], bl, acc_a[mt][nt], 0, 0, 0);
    }
  }

  // ---- ctx hi/lo -> global, linear [d][256 f] (f0..f0+3 contiguous per lane) ----
  unsigned short* ch = ctxh_g + (size_t)chunk * 16384;
  unsigned short* cl = ctxl_g + (size_t)chunk * 16384;
#pragma unroll
  for (int mt = 0; mt < 4; ++mt)
#pragma unroll
    for (int nt = 0; nt < 4; ++nt) {
      int f0 = wave * 64 + mt * 16 + quad * 4;
      int d = nt * 16 + fr;
      float v0 = acc_a[mt][nt][0], v1 = acc_a[mt][nt][1];
      float v2 = acc_a[mt][nt][2], v3 = acc_a[mt][nt][3];
      unsigned short h0 = f2bf(v0), h1 = f2bf(v1), h2 = f2bf(v2), h3 = f2bf(v3);
      uint2 whi, wlo;
      whi.x = (unsigned)h0 | ((unsigned)h1 << 16);
      whi.y = (unsigned)h2 | ((unsigned)h3 << 16);
      wlo.x = pack2(v0 - bf2f(h0), v1 - bf2f(h1));
      wlo.y = pack2(v2 - bf2f(h2), v3 - bf2f(h3));
      *(uint2*)(ch + d * 256 + f0) = whi;
      *(uint2*)(cl + d * 256 + f0) = wlo;
    }
}

// chunkB: q-pass (B-frags direct from global) -> QP(LDS); D; step B with ctx A-frags
// direct from global. LDS = 64K + 2.5K -> 2 blocks/CU.
__global__ __launch_bounds__(256, 2)
void chunkB(const unsigned short* __restrict__ qkv_bf,
            const unsigned short* __restrict__ projq,
            const unsigned short* __restrict__ ctxh_g,
            const unsigned short* __restrict__ ctxl_g,
            const float* __restrict__ ksum_g,
            unsigned short* __restrict__ attn_hi,
            unsigned short* __restrict__ attn_lo)
{
  __shared__ __align__(16) char smem[68096];
  unsigned short* QP = (unsigned short*)smem;       // [128 s][256 f] swz
  float* KS = (float*)(smem + 65536);               // [256]
  float* DP = (float*)(smem + 66560);               // [256]
  float* DI = (float*)(smem + 67584);               // [128]

  const int tid = threadIdx.x, lane = tid & 63, wave = tid >> 6;
  const int fr = lane & 15, quad = lane >> 4;
  const int chunk = blockIdx.x;
  const int b = chunk >> 8, h = (chunk >> 5) & 7, cc = chunk & 31;
  const int mbase = b * N_ + cc * CS_;
  const unsigned short* tqbase = qkv_bf + (size_t)mbase * 1024 + h * DH_;

  KS[tid] = ksum_g[(size_t)chunk * 256 + tid];

  // ---- q-pass: C[f][s] = projq @ t_q^T (B-frags direct from global) ----
  {
    bf16x8 bfr[2][2];
#pragma unroll
    for (int nt = 0; nt < 2; ++nt)
#pragma unroll
      for (int ks = 0; ks < 2; ++ks) {
        int s = wave * 32 + nt * 16 + fr;
        bfr[nt][ks] = *(const bf16x8*)(tqbase + (size_t)s * 1024 + ks * 32 + quad * 8);
      }
    f32x4 qa[16][2];
#pragma unroll
    for (int mt = 0; mt < 16; ++mt) { qa[mt][0] = {0,0,0,0}; qa[mt][1] = {0,0,0,0}; }
#pragma unroll
    for (int ks = 0; ks < 2; ++ks)
#pragma unroll
      for (int mt = 0; mt < 16; ++mt) {
        bf16x8 af = *(const bf16x8*)(projq + (size_t)(mt * 16 + fr) * 64 + ks * 32 + quad * 8);
        qa[mt][0] = __builtin_amdgcn_mfma_f32_16x16x32_bf16(af, bfr[0][ks], qa[mt][0], 0, 0, 0);
        qa[mt][1] = __builtin_amdgcn_mfma_f32_16x16x32_bf16(af, bfr[1][ks], qa[mt][1], 0, 0, 0);
      }
    // colmax over f, exp
#pragma unroll
    for (int nt = 0; nt < 2; ++nt) {
      float m = -1e30f;
#pragma unroll
      for (int mt = 0; mt < 16; ++mt)
#pragma unroll
        for (int r = 0; r < 4; ++r) m = fmaxf(m, qa[mt][nt][r]);
      m = fmaxf(m, __shfl_xor(m, 16, 64));
      m = fmaxf(m, __shfl_xor(m, 32, 64));
#pragma unroll
      for (int mt = 0; mt < 16; ++mt)
#pragma unroll
        for (int r = 0; r < 4; ++r) qa[mt][nt][r] = __expf(qa[mt][nt][r] - m);
    }
    // qp[s][f] write (4 consecutive f per lane)
#pragma unroll
    for (int nt = 0; nt < 2; ++nt) {
      int s = wave * 32 + nt * 16 + fr;
#pragma unroll
      for (int mt = 0; mt < 16; ++mt) {
        int g = mt * 2 + (quad >> 1);               // f>>3
        uint2 w;
        w.x = pack2(qa[mt][nt][0], qa[mt][nt][1]);
        w.y = pack2(qa[mt][nt][2], qa[mt][nt][3]);
        *(uint2*)(QP + s * 256 + ((g ^ (s & 15)) << 3) + (quad & 1) * 4) = w;
      }
    }
  }
  __syncthreads();

  // ---- D = qp . ksum (two f-halves in parallel over 256 threads) ----
  {
    int s = tid & 127, hf = tid >> 7;
    float dp = 0.f;
#pragma unroll 4
    for (int li = 0; li < 16; ++li) {
      int l = hf * 16 + li;
      bf16x8 qv = *(const bf16x8*)(QP + s * 256 + ((l ^ (s & 15)) << 3));
      f32x4 k0 = *(const f32x4*)(KS + l * 8);
      f32x4 k1 = *(const f32x4*)(KS + l * 8 + 4);
      dp += bf2f((unsigned short)qv[0]) * k0[0];
      dp += bf2f((unsigned short)qv[1]) * k0[1];
      dp += bf2f((unsigned short)qv[2]) * k0[2];
      dp += bf2f((unsigned short)qv[3]) * k0[3];
      dp += bf2f((unsigned short)qv[4]) * k1[0];
      dp += bf2f((unsigned short)qv[5]) * k1[1];
      dp += bf2f((unsigned short)qv[6]) * k1[2];
      dp += bf2f((unsigned short)qv[7]) * k1[3];
    }
    DP[hf * 128 + s] = dp;
  }
  __syncthreads();
  if (tid < 128) DI[tid] = 1.f / (DP[tid] + DP[128 + tid] + 1e-4f);
  __syncthreads();

  // ---- step B: C[m=d][n=s] = sum_f ctx[d][f]*qp[s][f]; scale; store attn ----
  const unsigned short* ch = ctxh_g + (size_t)chunk * 16384;
  const unsigned short* cl = ctxl_g + (size_t)chunk * 16384;
  f32x4 acc2[4][2];
#pragma unroll
  for (int i = 0; i < 4; ++i) { acc2[i][0] = {0,0,0,0}; acc2[i][1] = {0,0,0,0}; }
#pragma unroll
  for (int ks = 0; ks < 8; ++ks) {
    int l = ks * 4 + quad;
    bf16x8 ah[4], al[4];
#pragma unroll
    for (int mt = 0; mt < 4; ++mt) {
      int d = mt * 16 + fr;
      int off = d * 256 + ks * 32 + quad * 8;
      ah[mt] = *(const bf16x8*)(ch + off);
      al[mt] = *(const bf16x8*)(cl + off);
    }
#pragma unroll
    for (int nt = 0; nt < 2; ++nt) {
      int s = wave * 32 + nt * 16 + fr;
      bf16x8 bq = *(const bf16x8*)(QP + s * 256 + ((l ^ (s & 15)) << 3));
#pragma unroll
      for (int mt = 0; mt < 4; ++mt) {
        acc2[mt][nt] = __builtin_amdgcn_mfma_f32_16x16x32_bf16(ah[mt], bq, acc2[mt][nt], 0, 0, 0);
        acc2[mt][nt] = __builtin_amdgcn_mfma_f32_16x16x32_bf16(al[mt], bq, acc2[mt][nt], 0, 0, 0);
      }
    }
  }
#pragma unroll
  for (int nt = 0; nt < 2; ++nt) {
    int s = wave * 32 + nt * 16 + fr;
    float di = DI[s];
    size_t base = (size_t)(mbase + s) * 512 + h * DH_;
#pragma unroll
    for (int mt = 0; mt < 4; ++mt) {
      int d0 = mt * 16 + quad * 4;
      float o0 = acc2[mt][nt][0] * di, o1 = acc2[mt][nt][1] * di;
      float o2 = acc2[mt][nt][2] * di, o3 = acc2[mt][nt][3] * di;
      unsigned short h0 = f2bf(o0), h1 = f2bf(o1), h2 = f2bf(o2), h3 = f2bf(o3);
      uint2 whi, wlo;
      whi.x = (unsigned)h0 | ((unsigned)h1 << 16);
      whi.y = (unsigned)h2 | ((unsigned)h3 << 16);
      wlo.x = pack2(o0 - bf2f(h0), o1 - bf2f(h1));
      wlo.y = pack2(o2 - bf2f(h2), o3 - bf2f(h3));
      *(uint2*)(attn_hi + base + d0) = whi;
      *(uint2*)(attn_lo + base + d0) = wlo;
    }
  }
}

extern "C" void kernel_launch(void* const* d_in, const int* in_sizes, int n_in,
                              void* d_out, int out_size, void* d_ws, size_t ws_size,
                              hipStream_t stream)
{
  const float* x     = (const float*)d_in[0];
  const float* w_qkv = (const float*)d_in[1];
  const float* w_out = (const float*)d_in[2];
  const float* b_out = (const float*)d_in[3];
  const float* proj  = (const float*)d_in[4];
  float* out = (float*)d_out;

  // ws layout (235,929,600 B total):
  //  R0 @0:          qkv_bf bf16 [16384][1024] (q,k)   33,554,432
  //  R1 @33554432:   x_hi/x_lo bf16 [16384][512] each  33,554,432  -> later projq/projk + wout splits
  //  R2 @67108864:   wqkv splits (3 MB, dead after gemms) -> ctxh/ctxl [1024][64][256] 64 MB
  //  R3 @134217728:  attn_hi, attn_lo bf16 [16384][512] 33,554,432
  //  R4 @201326592:  vt_hi, vt_lo bf16 [1024][64][128] 33,554,432  (written by gemm_v epilogue)
  //  R5 @234881024:  ksum f32 [1024][256]               1,048,576
  char* ws = (char*)d_ws;
  unsigned short* qkv_bf = (unsigned short*)ws;
  unsigned short* x_hi   = (unsigned short*)(ws + 33554432);
  unsigned short* x_lo   = x_hi + (size_t)M_ * DIM_;
  unsigned short* wqkv_hi = (unsigned short*)(ws + 67108864);
  unsigned short* wqkv_lo = wqkv_hi + (size_t)(3*DIM_) * DIM_;
  unsigned short* ctxh_g  = (unsigned short*)(ws + 67108864);    // aliases wqkv (dead)
  unsigned short* ctxl_g  = (unsigned short*)(ws + 100663296);
  unsigned short* attn_hi = (unsigned short*)(ws + 134217728);
  unsigned short* attn_lo = attn_hi + (size_t)M_ * DIM_;
  unsigned short* vth_g  = (unsigned short*)(ws + 201326592);
  unsigned short* vtl_g  = (unsigned short*)(ws + 218103808);
  float*          ksum_g = (float*)(ws + 234881024);

  unsigned short* projq = x_hi;                         // x splits dead after gemm_v
  unsigned short* projk = projq + 16384;
  unsigned short* wout_hi = projk + 16384;
  unsigned short* wout_lo = wout_hi + (size_t)DIM_ * DIM_;

  // 1) splits
  split_kernel<<<dim3(M_*DIM_/4/256), 256, 0, stream>>>(x, x_hi, x_lo, M_*DIM_/4);
  split_kernel<<<dim3(3*DIM_*DIM_/4/256), 256, 0, stream>>>(w_qkv, wqkv_hi, wqkv_lo, 3*DIM_*DIM_/4);
  // 2) q,k = x @ w_qkv[0:1024]^T  (single bf16, bf16 out)
  mfma_gemm_nt<0,1><<<dim3(8, M_/128), 256, 0, stream>>>(
      x_hi, x_hi, wqkv_hi, wqkv_hi, qkv_bf, nullptr, DIM_, 1024, nullptr, nullptr);
  // 3) v = x @ w_qkv[1024:1536]^T (split) -> transposed hi/lo chunk layout directly
  mfma_gemm_nt<1,2><<<dim3(4, M_/128), 256, 0, stream>>>(
      x_hi, x_lo, wqkv_hi + (size_t)1024*DIM_, wqkv_lo + (size_t)1024*DIM_,
      nullptr, nullptr, DIM_, 0, vth_g, vtl_g);
  // 4) proj -> bf16 (q pre-scaled by 1/8); x splits dead now
  prep_proj<<<dim3(16), 256, 0, stream>>>(proj, projq, projk);
  // 5a) chunkA: k' -> kpT -> ctx (global)          [2 blocks/CU]
  chunkA<<<dim3(NCHUNK_), 256, 0, stream>>>(qkv_bf, projk, vth_g, vtl_g,
                                            ctxh_g, ctxl_g, ksum_g);
  // 5b) chunkB: q' -> D -> out = qp@ctx/D          [2 blocks/CU]
  chunkB<<<dim3(NCHUNK_), 256, 0, stream>>>(qkv_bf, projq, ctxh_g, ctxl_g, ksum_g,
                                            attn_hi, attn_lo);
  // 6) w_out split, then out = attn @ w_out^T + b_out (split)
  split_kernel<<<dim3(DIM_*DIM_/4/256), 256, 0, stream>>>(w_out, wout_hi, wout_lo, DIM_*DIM_/4);
  mfma_gemm_nt<1,0><<<dim3(4, M_/128), 256, 0, stream>>>(
      attn_hi, attn_lo, wout_hi, wout_lo, out, b_out, DIM_, DIM_, nullptr, nullptr);
}